// Round 2
// baseline (59.554 us; speedup 1.0000x reference)
//
#include <hip/hip_runtime.h>

// Problem constants (fixed by the reference):
//   B=8, N=256, IN_F=64, OUT_F=64, IN_E=32, OUT_E=64
#define BB    8
#define NN    256
#define INF   64
#define OUTF  64
#define INE   32
#define OUTE  64

using f4     = __attribute__((ext_vector_type(4))) float;
using f32x4  = __attribute__((ext_vector_type(4))) float;
using bf16x8 = __attribute__((ext_vector_type(8))) short;          // 8 bf16 = 4 VGPRs
using us4    = __attribute__((ext_vector_type(4))) unsigned short; // 8 B

// Scratch for the node projections (1 MB total) — device globals so we do not
// depend on ws_size. Fully overwritten by node_proj every call (deterministic).
__device__ float g_node_x[BB * NN * OUTF];   // emb_node@W_node + b_node (pre-relu)
__device__ float g_relu_sx[BB * NN * OUTF];  // relu(emb_node@W_nodes + b_nodes)

// f32 -> bf16, round-to-nearest-even (no header/type dependence).
static __device__ __forceinline__ unsigned short f2bf(float x) {
    unsigned u = __builtin_bit_cast(unsigned, x);
    u += 0x7fffu + ((u >> 16) & 1u);
    return (unsigned short)(u >> 16);
}

// ---------------------------------------------------------------------------
// Kernel 1: node projections (fp32 VALU — tiny: 67 MFLOP, ~1.5 MB traffic).
// ---------------------------------------------------------------------------
__global__ __launch_bounds__(256) void node_proj(
    const float* __restrict__ emb_node,  // [B*N, 64]
    const float* __restrict__ W1, const float* __restrict__ b1,
    const float* __restrict__ W2, const float* __restrict__ b2)
{
    __shared__ float sW1[64][64];
    __shared__ float sW2[64][64];
    __shared__ float sE[4][64];

    const int tid = threadIdx.x;

    const f4* w1v = (const f4*)W1;
    const f4* w2v = (const f4*)W2;
    f4* s1 = (f4*)&sW1[0][0];
    f4* s2 = (f4*)&sW2[0][0];
#pragma unroll
    for (int i = 0; i < 4; ++i) {
        s1[tid + i * 256] = w1v[tid + i * 256];
        s2[tid + i * 256] = w2v[tid + i * 256];
    }
    const int row0 = blockIdx.x * 4;
    if (tid < 64) ((f4*)&sE[0][0])[tid] = ((const f4*)(emb_node + row0 * 64))[tid];
    __syncthreads();

    const int s = tid >> 6;    // row within block (0..3)
    const int f = tid & 63;    // output feature
    float a1 = b1[f];
    float a2 = b2[f];
#pragma unroll
    for (int k = 0; k < 64; ++k) {
        const float e = sE[s][k];              // broadcast read
        a1 = fmaf(e, sW1[k][f], a1);
        a2 = fmaf(e, sW2[k][f], a2);
    }
    const int row = row0 + s;
    g_node_x[row * 64 + f]  = a1;              // pre-relu (used inside einsum)
    g_relu_sx[row * 64 + f] = fmaxf(a2, 0.f);
}

// ---------------------------------------------------------------------------
// Kernel 2: per (b,n) block. Edge GEMM [256m,32k]@[32k,64f] via bf16 MFMA
// (mfma_f32_16x16x32_bf16 — one instruction per 16x16 tile covers K=32).
// 8 waves; wave w owns rows [32w,32w+32) = 2 m-tiles x 4 f-tiles = 8 MFMAs.
// Fragment maps (gfx950): A: row=lane&15, k=(lane>>4)*8+i (16B contiguous in
// sEb[m][k]); B: col=lane&15, k=(lane>>4)*8+i (16B contiguous in sWt[f][k],
// W stored TRANSPOSED); C/D: col=lane&15, row=(lane>>4)*4+reg [guide m89].
// Epilogue fp32: relu->edge_out (nt stores), agg += A[m]*edge*node_x,
// shfl_xor reduce + LDS reduce over 8 waves -> node_out.
// LDS = 23.5 KB. 2048 blocks x 512 threads.
// ---------------------------------------------------------------------------
__global__ __launch_bounds__(512, 4) void edge_agg(
    const float* __restrict__ A,         // [B,N,N]
    const float* __restrict__ emb_edge,  // [B,N,N,32]
    const float* __restrict__ W_edge,    // [32,64]
    const float* __restrict__ b_edge,    // [64]
    float* __restrict__ node_out,        // [B,N,64]
    float* __restrict__ edge_out)        // [B,N,N,64]
{
    __shared__ unsigned short sEb[256][32]; // bf16 E tile, 16 KB
    __shared__ unsigned short sWt[64][32];  // bf16 W^T (f-major), 4 KB
    __shared__ float sA[256];               // 1 KB
    __shared__ float sRed[8][64];           // 2 KB

    const int tid = threadIdx.x;
    const int bn  = blockIdx.x;       // b*256+n
    const int b   = bn >> 8;

    // ---- stage emb_edge -> bf16 LDS: 2048 f4 chunks, 4 per thread ----
    const f4* embv = (const f4*)(emb_edge + (size_t)bn * (NN * INE));
#pragma unroll
    for (int it = 0; it < 4; ++it) {
        const int i = tid + it * 512;         // chunk: row m=i>>3, k-quad=i&7
        const f4 v = __builtin_nontemporal_load(embv + i);
        us4 h;
        h.x = f2bf(v.x); h.y = f2bf(v.y); h.z = f2bf(v.z); h.w = f2bf(v.w);
        *(us4*)&sEb[i >> 3][(i & 7) * 4] = h;  // contiguous 8B writes: conflict-free
    }
    // ---- stage W^T as bf16: thread t -> (f = t>>3, k-quad = t&7) ----
    {
        const int f  = tid >> 3;
        const int k0 = (tid & 7) * 4;
        us4 h;
        h.x = f2bf(W_edge[(k0 + 0) * 64 + f]);
        h.y = f2bf(W_edge[(k0 + 1) * 64 + f]);
        h.z = f2bf(W_edge[(k0 + 2) * 64 + f]);
        h.w = f2bf(W_edge[(k0 + 3) * 64 + f]);
        *(us4*)&sWt[f][k0] = h;
    }
    if (tid < 64) ((f4*)sA)[tid] = ((const f4*)(A + bn * NN))[tid];

    const int wave  = tid >> 6;   // 0..7
    const int lane  = tid & 63;
    const int lrow  = lane >> 4;  // 0..3
    const int lcol  = lane & 15;  // 0..15
    const int mbase = wave * 32;

    // bias per f-tile: D row varies with reg, bias depends only on f
    float bias[4];
#pragma unroll
    for (int ft = 0; ft < 4; ++ft) bias[ft] = b_edge[ft * 16 + lcol];

    __syncthreads();

    // ---- fragments: 2 A-frags (reused over ft), 4 B-frags (reused over mt) --
    bf16x8 afrag[2];
#pragma unroll
    for (int mt = 0; mt < 2; ++mt)
        afrag[mt] = *(const bf16x8*)&sEb[mbase + mt * 16 + lcol][lrow * 8];
    bf16x8 bfrag[4];
#pragma unroll
    for (int ft = 0; ft < 4; ++ft)
        bfrag[ft] = *(const bf16x8*)&sWt[ft * 16 + lcol][lrow * 8];

    f32x4 acc[2][4];
#pragma unroll
    for (int mt = 0; mt < 2; ++mt)
#pragma unroll
        for (int ft = 0; ft < 4; ++ft) {
            f32x4 c; c[0] = bias[ft]; c[1] = bias[ft]; c[2] = bias[ft]; c[3] = bias[ft];
            acc[mt][ft] = __builtin_amdgcn_mfma_f32_16x16x32_bf16(
                afrag[mt], bfrag[ft], c, 0, 0, 0);
        }

    // ---- epilogue: relu-store edge_out + weighted agg against node_x ----
    const float* nx = g_node_x + b * (NN * OUTF);
    float* eoutBase = edge_out + (size_t)bn * (NN * OUTE);
    float agg[4] = {0.f, 0.f, 0.f, 0.f};
#pragma unroll
    for (int mt = 0; mt < 2; ++mt) {
#pragma unroll
        for (int r = 0; r < 4; ++r) {
            const int m = mbase + mt * 16 + lrow * 4 + r;
            const float a = sA[m];                     // LDS broadcast
            const float* nxr = nx + m * 64 + lcol;     // L2-hot
            float* er = eoutBase + (size_t)m * 64 + lcol;
#pragma unroll
            for (int ft = 0; ft < 4; ++ft) {
                const float v = acc[mt][ft][r];        // pre-relu edge_x
                __builtin_nontemporal_store(fmaxf(v, 0.f), er + ft * 16);
                agg[ft] = fmaf(a * v, nxr[ft * 16], agg[ft]);
            }
        }
    }

    // ---- reduce: within wave (4 row-groups), then across 8 waves via LDS ----
#pragma unroll
    for (int ft = 0; ft < 4; ++ft) {
        float v = agg[ft];
        v += __shfl_xor(v, 16);
        v += __shfl_xor(v, 32);
        agg[ft] = v;
    }
    if (lane < 16) {
#pragma unroll
        for (int ft = 0; ft < 4; ++ft) sRed[wave][ft * 16 + lane] = agg[ft];
    }
    __syncthreads();

    if (tid < 64) {
        float s = 0.f;
#pragma unroll
        for (int w = 0; w < 8; ++w) s += sRed[w][tid];
        node_out[bn * 64 + tid] = fmaxf(s, 0.f) + g_relu_sx[bn * 64 + tid];
    }
}

// ---------------------------------------------------------------------------
extern "C" void kernel_launch(void* const* d_in, const int* in_sizes, int n_in,
                              void* d_out, int out_size, void* d_ws, size_t ws_size,
                              hipStream_t stream) {
    const float* A        = (const float*)d_in[0];
    const float* emb_node = (const float*)d_in[1];
    const float* emb_edge = (const float*)d_in[2];
    const float* W_node   = (const float*)d_in[3];
    const float* b_node   = (const float*)d_in[4];
    const float* W_nodes  = (const float*)d_in[5];
    const float* b_nodes  = (const float*)d_in[6];
    const float* W_edge   = (const float*)d_in[7];
    const float* b_edge   = (const float*)d_in[8];

    float* node_out = (float*)d_out;                 // [8,256,64]
    float* edge_out = node_out + BB * NN * OUTF;     // [8,256,256,64]

    node_proj<<<(BB * NN) / 4, 256, 0, stream>>>(emb_node, W_node, b_node, W_nodes, b_nodes);
    edge_agg<<<BB * NN, 512, 0, stream>>>(A, emb_edge, W_edge, b_edge, node_out, edge_out);
}